// Round 1
// baseline (110.366 us; speedup 1.0000x reference)
//
#include <hip/hip_runtime.h>

// Problem constants
#define NB 8
#define CH 64
#define KP 8          // K = C/8
#define HWP 4096      // H*W
#define SCHUNK 8      // q-split factor (parallelism)
#define QCH (HWP / SCHUNK)  // 512 q per chunk

// Workspace layout (float offsets)
#define WS_F   0                              // [NB][HWP][KP]
#define WS_G   (WS_F + NB * HWP * KP)         // [NB][HWP][KP]
#define WS_S   (WS_G + NB * HWP * KP)         // [NB][HWP]
#define WS_ATT (WS_S + NB * HWP)              // [NB][HWP]
#define WS_PM  (WS_ATT + NB * HWP)            // [NB][HWP][SCHUNK]
#define WS_PL  (WS_PM + NB * HWP * SCHUNK)
#define WS_PA  (WS_PL + NB * HWP * SCHUNK)
// total = 2*262144 + 2*32768 + 3*262144 = 1,376,256 floats = 5.25 MiB

// ---------------------------------------------------------------------------
// Kernel 1: 1x1-conv projections. One thread per pixel p of batch n.
// f[n][p][k] = sum_c Wf[k][c] * x[n][c][p] + bf[k]   (same for g, s)
// x reads are coalesced across lanes (p contiguous); weights are wave-uniform
// (n is uniform per block) -> scalar loads.
// ---------------------------------------------------------------------------
__global__ __launch_bounds__(256) void proj_kernel(
    const float* __restrict__ x,
    const float* __restrict__ Wf, const float* __restrict__ bf,
    const float* __restrict__ Wg, const float* __restrict__ bg,
    const float* __restrict__ Ws, const float* __restrict__ bs,
    float* __restrict__ ws)
{
    int blk = blockIdx.x;                 // 128 blocks: 16 per batch
    int n = blk >> 4;
    int p = ((blk & 15) << 8) + threadIdx.x;
    const float* xp = x + (size_t)n * CH * HWP + p;

    float accf[KP], accg[KP], accs;
#pragma unroll
    for (int k = 0; k < KP; ++k) { accf[k] = bf[k]; accg[k] = bg[k]; }
    accs = bs[0];

#pragma unroll 4
    for (int c = 0; c < CH; ++c) {
        float xv = xp[(size_t)c * HWP];
#pragma unroll
        for (int k = 0; k < KP; ++k) {
            accf[k] = fmaf(Wf[k * CH + c], xv, accf[k]);
            accg[k] = fmaf(Wg[k * CH + c], xv, accg[k]);
        }
        accs = fmaf(Ws[c], xv, accs);
    }

    float* fo = ws + WS_F + ((size_t)n * HWP + p) * KP;
    float* go = ws + WS_G + ((size_t)n * HWP + p) * KP;
    *(float4*)(fo)     = make_float4(accf[0], accf[1], accf[2], accf[3]);
    *(float4*)(fo + 4) = make_float4(accf[4], accf[5], accf[6], accf[7]);
    *(float4*)(go)     = make_float4(accg[0], accg[1], accg[2], accg[3]);
    *(float4*)(go + 4) = make_float4(accg[4], accg[5], accg[6], accg[7]);
    ws[WS_S + (size_t)n * HWP + p] = accs;
}

// ---------------------------------------------------------------------------
// Kernel 2: flash-attention partials. Each block: one batch n, a 256-row
// p-tile, one 512-col q-chunk. g/s chunk staged in LDS; inner loop reads are
// wave-uniform (broadcast, conflict-free). Online softmax per thread (1 row).
// ---------------------------------------------------------------------------
__global__ __launch_bounds__(256) void attn_partial_kernel(float* __restrict__ ws)
{
    __shared__ float gld[QCH * KP];   // 16 KiB
    __shared__ float sld[QCH];        // 2 KiB

    int blk = blockIdx.x;             // 1024 blocks = NB(8) * ptiles(16) * SCHUNK(8)
    int chunk = blk & (SCHUNK - 1);
    int ptile = (blk >> 3) & 15;
    int n = blk >> 7;
    int p = (ptile << 8) + threadIdx.x;
    int q0 = chunk * QCH;

    // cooperative load of g[n][q0:q0+QCH][:] and s[n][q0:q0+QCH]
    const float4* gsrc = (const float4*)(ws + WS_G + ((size_t)n * HWP + q0) * KP);
    float4* gdst = (float4*)gld;
#pragma unroll
    for (int i = 0; i < (QCH * KP / 4) / 256; ++i)
        gdst[threadIdx.x + i * 256] = gsrc[threadIdx.x + i * 256];
    if (threadIdx.x < QCH / 4)
        ((float4*)sld)[threadIdx.x] =
            ((const float4*)(ws + WS_S + (size_t)n * HWP + q0))[threadIdx.x];

    // this thread's f row (8 floats)
    const float4* fp = (const float4*)(ws + WS_F + ((size_t)n * HWP + p) * KP);
    float4 f0 = fp[0], f1 = fp[1];

    __syncthreads();

    float m = -1e30f, l = 0.f, acc = 0.f;
#pragma unroll 4
    for (int q = 0; q < QCH; ++q) {
        float4 g0 = *(const float4*)(gld + q * KP);
        float4 g1 = *(const float4*)(gld + q * KP + 4);
        float sc = f0.x * g0.x + f0.y * g0.y + f0.z * g0.z + f0.w * g0.w
                 + f1.x * g1.x + f1.y * g1.y + f1.z * g1.z + f1.w * g1.w;
        float mn   = fmaxf(m, sc);
        float corr = __expf(m - mn);
        float e    = __expf(sc - mn);
        l   = fmaf(l, corr, e);
        acc = fmaf(acc, corr, e * sld[q]);
        m = mn;
    }

    size_t pidx = ((size_t)n * HWP + p) * SCHUNK + chunk;
    ws[WS_PM + pidx] = m;
    ws[WS_PL + pidx] = l;
    ws[WS_PA + pidx] = acc;
}

// ---------------------------------------------------------------------------
// Kernel 3: merge the SCHUNK partial softmax states per row; write att_map
// (first output) and stash att for the epilogue.
// ---------------------------------------------------------------------------
__global__ __launch_bounds__(256) void merge_kernel(float* __restrict__ ws,
                                                    float* __restrict__ out_att)
{
    int i = blockIdx.x * 256 + threadIdx.x;   // row index over NB*HWP
    const float* pm = ws + WS_PM + (size_t)i * SCHUNK;
    const float* pl = ws + WS_PL + (size_t)i * SCHUNK;
    const float* pa = ws + WS_PA + (size_t)i * SCHUNK;

    float m = -1e30f;
#pragma unroll
    for (int c = 0; c < SCHUNK; ++c) m = fmaxf(m, pm[c]);
    float l = 0.f, a = 0.f;
#pragma unroll
    for (int c = 0; c < SCHUNK; ++c) {
        float w = __expf(pm[c] - m);
        l = fmaf(pl[c], w, l);
        a = fmaf(pa[c], w, a);
    }
    float att = a / l;
    out_att[i] = att;            // att_map output [N,1,H,W]
    ws[WS_ATT + i] = att;
}

// ---------------------------------------------------------------------------
// Kernel 4: epilogue  out[n][c][p] = att[n][p]*gamma + x[n][c][p], float4.
// ---------------------------------------------------------------------------
__global__ __launch_bounds__(256) void epilogue_kernel(
    const float* __restrict__ x, const float* __restrict__ ws,
    const float* __restrict__ gamma, float* __restrict__ out)
{
    size_t i = (size_t)blockIdx.x * 256 + threadIdx.x;  // float4 index
    size_t e = i * 4;
    int n = (int)(e >> 18);          // / (CH*HWP) = 262144
    int p = (int)(e & (HWP - 1));
    float gm = gamma[0];
    float4 a4 = *(const float4*)(ws + WS_ATT + (size_t)n * HWP + p);
    float4 x4 = *(const float4*)(x + e);
    float4 o;
    o.x = fmaf(a4.x, gm, x4.x);
    o.y = fmaf(a4.y, gm, x4.y);
    o.z = fmaf(a4.z, gm, x4.z);
    o.w = fmaf(a4.w, gm, x4.w);
    *(float4*)(out + e) = o;
}

extern "C" void kernel_launch(void* const* d_in, const int* in_sizes, int n_in,
                              void* d_out, int out_size, void* d_ws, size_t ws_size,
                              hipStream_t stream) {
    const float* x     = (const float*)d_in[0];
    const float* Wf    = (const float*)d_in[1];
    const float* bf    = (const float*)d_in[2];
    const float* Wg    = (const float*)d_in[3];
    const float* bg    = (const float*)d_in[4];
    const float* Ws    = (const float*)d_in[5];
    const float* bs    = (const float*)d_in[6];
    const float* gamma = (const float*)d_in[7];
    float* out = (float*)d_out;
    float* ws  = (float*)d_ws;

    // d_out layout: att_map [NB*HWP] then output [NB*CH*HWP]
    proj_kernel<<<NB * (HWP / 256), 256, 0, stream>>>(x, Wf, bf, Wg, bg, Ws, bs, ws);
    attn_partial_kernel<<<NB * (HWP / 256) * SCHUNK, 256, 0, stream>>>(ws);
    merge_kernel<<<NB * HWP / 256, 256, 0, stream>>>(ws, out);
    epilogue_kernel<<<(NB * CH * HWP / 4) / 256, 256, 0, stream>>>(
        x, ws, gamma, out + NB * HWP);
}

// Round 2
// 54.647 us; speedup vs baseline: 2.0196x; 2.0196x over previous
//
#include <hip/hip_runtime.h>

// Problem constants
#define NB 8
#define CH 64
#define KP 8            // K = C/8
#define HWP 4096        // H*W
#define QSPLIT 8        // q-split factor (parallelism)
#define QCHUNK (HWP / QSPLIT)   // 512 q per chunk
#define NHW (NB * HWP)  // 32768

typedef float f32x4 __attribute__((ext_vector_type(4)));
typedef __bf16 bf16x8 __attribute__((ext_vector_type(8)));
typedef short short8v __attribute__((ext_vector_type(8)));

// Workspace layout (float offsets)
#define WS_FB  0                        // f bf16 [NB][HWP][8]  (= NHW*4 floats)
#define WS_GB  (WS_FB + NHW * 4)        // g bf16 [NB][HWP][8]
#define WS_S   (WS_GB + NHW * 4)        // s f32  [NB][HWP]
#define WS_ATT (WS_S + NHW)             // att f32 [NB][HWP]
#define WS_PM  (WS_ATT + NHW)           // partial m2  [QSPLIT][NHW]  (log2 domain)
#define WS_PL  (WS_PM + QSPLIT * NHW)   // partial l
#define WS_PA  (WS_PL + QSPLIT * NHW)   // partial acc
// total = 2*131072 + 2*32768 + 3*262144 = 1,114,112 floats = 4.25 MiB

// ---------------------------------------------------------------------------
// Kernel 1: 1x1-conv projections. One thread per pixel. Writes f,g as bf16
// rows of 8 (16B, MFMA-fragment-ready) and s as f32.
// ---------------------------------------------------------------------------
__global__ __launch_bounds__(128) void proj_kernel(
    const float* __restrict__ x,
    const float* __restrict__ Wf, const float* __restrict__ bf,
    const float* __restrict__ Wg, const float* __restrict__ bg,
    const float* __restrict__ Ws, const float* __restrict__ bs,
    float* __restrict__ ws)
{
    int blk = blockIdx.x;                 // 256 blocks: 32 per batch
    int n = blk >> 5;
    int p = ((blk & 31) << 7) + threadIdx.x;
    const float* xp = x + (size_t)n * CH * HWP + p;

    float accf[KP], accg[KP], accs;
#pragma unroll
    for (int k = 0; k < KP; ++k) { accf[k] = bf[k]; accg[k] = bg[k]; }
    accs = bs[0];

#pragma unroll 8
    for (int c = 0; c < CH; ++c) {
        float xv = xp[(size_t)c * HWP];
#pragma unroll
        for (int k = 0; k < KP; ++k) {
            accf[k] = fmaf(Wf[k * CH + c], xv, accf[k]);
            accg[k] = fmaf(Wg[k * CH + c], xv, accg[k]);
        }
        accs = fmaf(Ws[c], xv, accs);
    }

    bf16x8 fv, gv;
#pragma unroll
    for (int k = 0; k < KP; ++k) { fv[k] = (__bf16)accf[k]; gv[k] = (__bf16)accg[k]; }

    ushort* fb = (ushort*)(ws + WS_FB) + (size_t)(n * HWP + p) * 8;
    ushort* gb = (ushort*)(ws + WS_GB) + (size_t)(n * HWP + p) * 8;
    *(short8v*)fb = __builtin_bit_cast(short8v, fv);
    *(short8v*)gb = __builtin_bit_cast(short8v, gv);
    ws[WS_S + (size_t)n * HWP + p] = accs;
}

// ---------------------------------------------------------------------------
// Kernel 2: MFMA flash-attention partials.
// Block: batch n, 256 p-rows, one 512-q chunk. 4 waves; each wave owns 64 p
// rows = 4 p-tiles of 16. Per q-tile of 16: one A-frag (g rows, K=8 real of
// 32) + 4 MFMAs (S^T tiles). Lane-local online softmax (defer-max) over the
// 4 C-regs (4 q rows for p = col). Butterfly-merge lane groups at the end.
// ---------------------------------------------------------------------------
__global__ __launch_bounds__(256) void attn_mfma_kernel(float* __restrict__ ws)
{
    __shared__ alignas(16) ushort g_lds[(QCHUNK + 1) * 8];  // +1 zero row
    __shared__ alignas(16) float  s_lds[QCHUNK];

    const int b     = blockIdx.x;          // 1024 = 8n * 16pblk * 8chunk
    const int chunk = b & (QSPLIT - 1);
    const int pblk  = (b >> 3) & 15;
    const int n     = b >> 7;
    const int tid   = threadIdx.x;
    const int lane  = tid & 63;
    const int wv    = tid >> 6;
    const int hi4   = lane >> 4;
    const int q0    = chunk * QCHUNK;

    // ---- stage g chunk (bf16, 8 KiB) + zero row + s chunk (2 KiB) ----
    {
        const float4* gsrc = (const float4*)(ws + WS_GB) + ((size_t)n * HWP + q0);
        float4* gdst = (float4*)g_lds;
        gdst[tid]        = gsrc[tid];
        gdst[tid + 256]  = gsrc[tid + 256];
        if (tid == 0) gdst[QCHUNK] = make_float4(0.f, 0.f, 0.f, 0.f);
        if (tid < QCHUNK / 4)
            ((float4*)s_lds)[tid] =
                ((const float4*)(ws + WS_S + (size_t)n * HWP + q0))[tid];
    }

    // ---- B-fragments: f rows for this wave's 4 p-tiles (lanes 0-15 real) ----
    const int p0 = (pblk << 8) + (wv << 6);
    const ushort* fbase = (const ushort*)(ws + WS_FB) + (size_t)n * HWP * 8;
    bf16x8 bfrag[4];
#pragma unroll
    for (int t = 0; t < 4; ++t) {
        short8v v = {0, 0, 0, 0, 0, 0, 0, 0};
        if (lane < 16)
            v = *(const short8v*)(fbase + (size_t)(p0 + t * 16 + lane) * 8);
        bfrag[t] = __builtin_bit_cast(bf16x8, v);
    }

    __syncthreads();

    const float L2E = 1.4426950408889634f;
    const f32x4 czero = {0.f, 0.f, 0.f, 0.f};
    float m2[4], lsum[4], acc[4];
#pragma unroll
    for (int t = 0; t < 4; ++t) { m2[t] = -3.0e38f; lsum[t] = 0.f; acc[t] = 0.f; }

#pragma unroll 2
    for (int qt = 0; qt < QCHUNK / 16; ++qt) {
        const int qq = qt << 4;
        // A-frag: g rows (lanes 0-15), zero row for lanes 16-63 (k>=8 slots)
        int arow = (lane < 16) ? (qq + lane) : QCHUNK;
        short8v araw = *(const short8v*)(g_lds + (size_t)arow * 8);
        bf16x8 afrag = __builtin_bit_cast(bf16x8, araw);
        float4 sv = *(const float4*)(s_lds + qq + (hi4 << 2));

#pragma unroll
        for (int t = 0; t < 4; ++t) {
            f32x4 c = __builtin_amdgcn_mfma_f32_16x16x32_bf16(
                afrag, bfrag[t], czero, 0, 0, 0);
            // c[r] = S[p0+t*16+(lane&15)][q0+qq+4*hi4+r]
            float tm = fmaxf(fmaxf(c[0], c[1]), fmaxf(c[2], c[3]));
            float t2 = fmaf(tm, L2E, -m2[t]);
            if (__any(t2 > 8.0f)) {                 // rare rescale (defer-max)
                float nm   = fmaxf(m2[t], tm * L2E);
                float corr = __builtin_amdgcn_exp2f(m2[t] - nm);
                lsum[t] *= corr; acc[t] *= corr; m2[t] = nm;
            }
            float e0 = __builtin_amdgcn_exp2f(fmaf(c[0], L2E, -m2[t]));
            float e1 = __builtin_amdgcn_exp2f(fmaf(c[1], L2E, -m2[t]));
            float e2 = __builtin_amdgcn_exp2f(fmaf(c[2], L2E, -m2[t]));
            float e3 = __builtin_amdgcn_exp2f(fmaf(c[3], L2E, -m2[t]));
            lsum[t] += (e0 + e1) + (e2 + e3);
            acc[t] = fmaf(e0, sv.x, acc[t]);
            acc[t] = fmaf(e1, sv.y, acc[t]);
            acc[t] = fmaf(e2, sv.z, acc[t]);
            acc[t] = fmaf(e3, sv.w, acc[t]);
        }
    }

    // ---- merge the 4 lane-groups (same p, disjoint q rows): xor 16, 32 ----
#pragma unroll
    for (int t = 0; t < 4; ++t) {
#pragma unroll
        for (int off = 16; off <= 32; off <<= 1) {
            float mo = __shfl_xor(m2[t],   off, 64);
            float lo = __shfl_xor(lsum[t], off, 64);
            float ao = __shfl_xor(acc[t],  off, 64);
            float nm = fmaxf(m2[t], mo);
            float ca = __builtin_amdgcn_exp2f(m2[t] - nm);
            float cb = __builtin_amdgcn_exp2f(mo - nm);
            lsum[t] = lsum[t] * ca + lo * cb;
            acc[t]  = acc[t]  * ca + ao * cb;
            m2[t]   = nm;
        }
        if (lane < 16) {
            size_t idx = (size_t)chunk * NHW + (size_t)n * HWP + p0 + t * 16 + lane;
            ws[WS_PM + idx] = m2[t];
            ws[WS_PL + idx] = lsum[t];
            ws[WS_PA + idx] = acc[t];
        }
    }
}

// ---------------------------------------------------------------------------
// Kernel 3: merge QSPLIT partial states per row (log2 domain); write att_map.
// ---------------------------------------------------------------------------
__global__ __launch_bounds__(256) void merge_kernel(float* __restrict__ ws,
                                                    float* __restrict__ out_att)
{
    int i = blockIdx.x * 256 + threadIdx.x;   // row over NHW
    float pm[QSPLIT], pl[QSPLIT], pa[QSPLIT];
#pragma unroll
    for (int c = 0; c < QSPLIT; ++c) {
        pm[c] = ws[WS_PM + (size_t)c * NHW + i];
        pl[c] = ws[WS_PL + (size_t)c * NHW + i];
        pa[c] = ws[WS_PA + (size_t)c * NHW + i];
    }
    float m = -3.0e38f;
#pragma unroll
    for (int c = 0; c < QSPLIT; ++c) m = fmaxf(m, pm[c]);
    float l = 0.f, a = 0.f;
#pragma unroll
    for (int c = 0; c < QSPLIT; ++c) {
        float w = __builtin_amdgcn_exp2f(pm[c] - m);
        l = fmaf(pl[c], w, l);
        a = fmaf(pa[c], w, a);
    }
    float att = a / l;
    out_att[i] = att;
    ws[WS_ATT + i] = att;
}

// ---------------------------------------------------------------------------
// Kernel 4: epilogue  out[n][c][p] = att[n][p]*gamma + x[n][c][p], float4.
// ---------------------------------------------------------------------------
__global__ __launch_bounds__(256) void epilogue_kernel(
    const float* __restrict__ x, const float* __restrict__ ws,
    const float* __restrict__ gamma, float* __restrict__ out)
{
    size_t i = (size_t)blockIdx.x * 256 + threadIdx.x;  // float4 index
    size_t e = i * 4;
    int n = (int)(e >> 18);          // / (CH*HWP)
    int p = (int)(e & (HWP - 1));
    float gm = gamma[0];
    float4 a4 = *(const float4*)(ws + WS_ATT + (size_t)n * HWP + p);
    float4 x4 = *(const float4*)(x + e);
    float4 o;
    o.x = fmaf(a4.x, gm, x4.x);
    o.y = fmaf(a4.y, gm, x4.y);
    o.z = fmaf(a4.z, gm, x4.z);
    o.w = fmaf(a4.w, gm, x4.w);
    *(float4*)(out + e) = o;
}

extern "C" void kernel_launch(void* const* d_in, const int* in_sizes, int n_in,
                              void* d_out, int out_size, void* d_ws, size_t ws_size,
                              hipStream_t stream) {
    const float* x     = (const float*)d_in[0];
    const float* Wf    = (const float*)d_in[1];
    const float* bf    = (const float*)d_in[2];
    const float* Wg    = (const float*)d_in[3];
    const float* bg    = (const float*)d_in[4];
    const float* Ws    = (const float*)d_in[5];
    const float* bs    = (const float*)d_in[6];
    const float* gamma = (const float*)d_in[7];
    float* out = (float*)d_out;
    float* ws  = (float*)d_ws;

    // d_out layout: att_map [NB*HWP] then output [NB*CH*HWP]
    proj_kernel<<<NB * (HWP / 128), 128, 0, stream>>>(x, Wf, bf, Wg, bg, Ws, bs, ws);
    attn_mfma_kernel<<<NB * 16 * QSPLIT, 256, 0, stream>>>(ws);
    merge_kernel<<<NHW / 256, 256, 0, stream>>>(ws, out);
    epilogue_kernel<<<(NB * CH * HWP / 4) / 256, 256, 0, stream>>>(
        x, ws, gamma, out + NHW);
}

// Round 3
// 47.783 us; speedup vs baseline: 2.3097x; 1.1437x over previous
//
#include <hip/hip_runtime.h>

// Problem constants
#define NB 8
#define CH 64
#define KP 8            // K = C/8
#define HWP 4096        // H*W
#define QSPLIT 16       // q-split factor (parallelism)
#define QCHUNK (HWP / QSPLIT)   // 256 q per chunk
#define NHW (NB * HWP)  // 32768

typedef float f32x16 __attribute__((ext_vector_type(16)));
typedef __bf16 bf16x8 __attribute__((ext_vector_type(8)));
typedef short short8v __attribute__((ext_vector_type(8)));

// Workspace layout (float offsets)
#define WS_FB  0                        // f bf16 [NB][HWP][8], pre-scaled by log2(e)
#define WS_GB  (WS_FB + NHW * 4)        // g bf16 [NB][HWP][8]
#define WS_S   (WS_GB + NHW * 4)        // s f32  [NB][HWP]
#define WS_ATT (WS_S + NHW)             // att f32 [NB][HWP]
#define WS_PL  (WS_ATT + NHW)           // partial l   [QSPLIT][NHW]
#define WS_PA  (WS_PL + QSPLIT * NHW)   // partial acc [QSPLIT][NHW]
// total = 2*131072 + 2*32768 + 2*524288 = 1,376,256 floats = 5.25 MiB

// ---------------------------------------------------------------------------
// Kernel 1: 1x1-conv projections. One thread per pixel. f is pre-scaled by
// log2(e) so the MFMA score is directly the exp2 argument. f,g stored as
// bf16 rows of 8 (16B, MFMA-fragment-ready); s as f32.
// ---------------------------------------------------------------------------
__global__ __launch_bounds__(256) void proj_kernel(
    const float* __restrict__ x,
    const float* __restrict__ Wf, const float* __restrict__ bf,
    const float* __restrict__ Wg, const float* __restrict__ bg,
    const float* __restrict__ Ws, const float* __restrict__ bs,
    float* __restrict__ ws)
{
    int blk = blockIdx.x;                 // 128 blocks: 16 per batch
    int n = blk >> 4;
    int p = ((blk & 15) << 8) + threadIdx.x;
    const float* xp = x + (size_t)n * CH * HWP + p;

    float accf[KP], accg[KP], accs;
#pragma unroll
    for (int k = 0; k < KP; ++k) { accf[k] = bf[k]; accg[k] = bg[k]; }
    accs = bs[0];

#pragma unroll 16
    for (int c = 0; c < CH; ++c) {
        float xv = xp[(size_t)c * HWP];
#pragma unroll
        for (int k = 0; k < KP; ++k) {
            accf[k] = fmaf(Wf[k * CH + c], xv, accf[k]);
            accg[k] = fmaf(Wg[k * CH + c], xv, accg[k]);
        }
        accs = fmaf(Ws[c], xv, accs);
    }

    const float L2E = 1.4426950408889634f;
    bf16x8 fv, gv;
#pragma unroll
    for (int k = 0; k < KP; ++k) {
        fv[k] = (__bf16)(accf[k] * L2E);
        gv[k] = (__bf16)accg[k];
    }

    ushort* fb = (ushort*)(ws + WS_FB) + (size_t)(n * HWP + p) * 8;
    ushort* gb = (ushort*)(ws + WS_GB) + (size_t)(n * HWP + p) * 8;
    *(short8v*)fb = __builtin_bit_cast(short8v, fv);
    *(short8v*)gb = __builtin_bit_cast(short8v, gv);
    ws[WS_S + (size_t)n * HWP + p] = accs;
}

// ---------------------------------------------------------------------------
// Kernel 2: MFMA flash-attention partials (no-max softmax).
// Block: batch n, 256 p-rows, one 256-q chunk. 4 waves; wave owns 64 p rows.
// Per 32-q tile: one A-frag (g rows; lanes 32-63 = zero k-half) + 2 MFMAs
// (32x32x16, S^T[32q][32p] each). Per element: exp2 + add + fma. Partial
// (l, acc) per p, merged across the hi/lo lane halves with one xor-32.
// ---------------------------------------------------------------------------
__global__ __launch_bounds__(256) void attn_mfma_kernel(float* __restrict__ ws)
{
    __shared__ alignas(16) ushort g_lds[(QCHUNK + 1) * 8];  // +1 zero row
    __shared__ alignas(16) float  s_lds[QCHUNK];

    const int b     = blockIdx.x;          // 2048 = 8n * 16pblk * 16chunk
    const int chunk = b & (QSPLIT - 1);
    const int pblk  = (b >> 4) & 15;
    const int n     = b >> 8;
    const int tid   = threadIdx.x;
    const int lane  = tid & 63;
    const int wv    = tid >> 6;
    const int l31   = lane & 31;
    const int hi    = lane >> 5;
    const int q0    = chunk * QCHUNK;

    // ---- stage g chunk (bf16, 4 KiB) + zero row + s chunk (1 KiB) ----
    {
        const float4* gsrc = (const float4*)(ws + WS_GB) + ((size_t)n * HWP + q0);
        float4* gdst = (float4*)g_lds;
        gdst[tid] = gsrc[tid];
        if (tid == 0) gdst[QCHUNK] = make_float4(0.f, 0.f, 0.f, 0.f);
        if (tid < QCHUNK / 4)
            ((float4*)s_lds)[tid] =
                ((const float4*)(ws + WS_S + (size_t)n * HWP + q0))[tid];
    }

    // ---- B-fragments: f rows for this wave's 64 p (lanes 0-31 real) ----
    const int p0 = (pblk << 8) + (wv << 6);
    const ushort* fbase = (const ushort*)(ws + WS_FB) + (size_t)n * HWP * 8;
    short8v z8 = {0, 0, 0, 0, 0, 0, 0, 0};
    bf16x8 bfrag0 = __builtin_bit_cast(bf16x8,
        hi ? z8 : *(const short8v*)(fbase + (size_t)(p0 + l31) * 8));
    bf16x8 bfrag1 = __builtin_bit_cast(bf16x8,
        hi ? z8 : *(const short8v*)(fbase + (size_t)(p0 + 32 + l31) * 8));

    __syncthreads();

    const f32x16 czero = {0.f};
    float l0a = 0.f, l0b = 0.f, a0 = 0.f;
    float l1a = 0.f, l1b = 0.f, a1 = 0.f;

#pragma unroll 2
    for (int qt = 0; qt < QCHUNK / 32; ++qt) {     // 8 iterations
        const int qq = qt << 5;
        // A-frag: g rows (lanes 0-31), zero row for lanes 32-63 (k>=8)
        int arow = hi ? QCHUNK : (qq + l31);
        bf16x8 afrag = __builtin_bit_cast(bf16x8,
            *(const short8v*)(g_lds + (size_t)arow * 8));
        // s for the 16 q-rows this lane's D regs cover
        float4 s0 = *(const float4*)(s_lds + qq +      (hi << 2));
        float4 s1 = *(const float4*)(s_lds + qq + 8  + (hi << 2));
        float4 s2 = *(const float4*)(s_lds + qq + 16 + (hi << 2));
        float4 s3 = *(const float4*)(s_lds + qq + 24 + (hi << 2));

        f32x16 c0 = __builtin_amdgcn_mfma_f32_32x32x16_bf16(afrag, bfrag0, czero, 0, 0, 0);
        f32x16 c1 = __builtin_amdgcn_mfma_f32_32x32x16_bf16(afrag, bfrag1, czero, 0, 0, 0);
        // c[r] = S2[q0+qq+(r&3)+8*(r>>2)+4*hi][p0(+32)+l31]  (log2-domain score)
#define PROC(cr, sval, l, a) { float e = __builtin_amdgcn_exp2f(cr); l += e; a = fmaf(e, sval, a); }
        PROC(c0[0],  s0.x, l0a, a0)  PROC(c0[1],  s0.y, l0b, a0)
        PROC(c0[2],  s0.z, l0a, a0)  PROC(c0[3],  s0.w, l0b, a0)
        PROC(c0[4],  s1.x, l0a, a0)  PROC(c0[5],  s1.y, l0b, a0)
        PROC(c0[6],  s1.z, l0a, a0)  PROC(c0[7],  s1.w, l0b, a0)
        PROC(c0[8],  s2.x, l0a, a0)  PROC(c0[9],  s2.y, l0b, a0)
        PROC(c0[10], s2.z, l0a, a0)  PROC(c0[11], s2.w, l0b, a0)
        PROC(c0[12], s3.x, l0a, a0)  PROC(c0[13], s3.y, l0b, a0)
        PROC(c0[14], s3.z, l0a, a0)  PROC(c0[15], s3.w, l0b, a0)
        PROC(c1[0],  s0.x, l1a, a1)  PROC(c1[1],  s0.y, l1b, a1)
        PROC(c1[2],  s0.z, l1a, a1)  PROC(c1[3],  s0.w, l1b, a1)
        PROC(c1[4],  s1.x, l1a, a1)  PROC(c1[5],  s1.y, l1b, a1)
        PROC(c1[6],  s1.z, l1a, a1)  PROC(c1[7],  s1.w, l1b, a1)
        PROC(c1[8],  s2.x, l1a, a1)  PROC(c1[9],  s2.y, l1b, a1)
        PROC(c1[10], s2.z, l1a, a1)  PROC(c1[11], s2.w, l1b, a1)
        PROC(c1[12], s3.x, l1a, a1)  PROC(c1[13], s3.y, l1b, a1)
        PROC(c1[14], s3.z, l1a, a1)  PROC(c1[15], s3.w, l1b, a1)
#undef PROC
    }

    float l0 = l0a + l0b, l1 = l1a + l1b;
    // merge hi/lo lane halves (same p, disjoint q rows)
    l0 += __shfl_xor(l0, 32, 64);
    a0 += __shfl_xor(a0, 32, 64);
    l1 += __shfl_xor(l1, 32, 64);
    a1 += __shfl_xor(a1, 32, 64);

    // lanes 0-31 write D0's p, lanes 32-63 write D1's p (coalesced 64 floats)
    size_t base = (size_t)chunk * NHW + (size_t)n * HWP + p0;
    float lw = hi ? l1 : l0;
    float aw = hi ? a1 : a0;
    ws[WS_PL + base + lane] = lw;
    ws[WS_PA + base + lane] = aw;
}

// ---------------------------------------------------------------------------
// Kernel 3: merge QSPLIT partial (l, acc) per row; write att_map.
// ---------------------------------------------------------------------------
__global__ __launch_bounds__(256) void merge_kernel(float* __restrict__ ws,
                                                    float* __restrict__ out_att)
{
    int i = blockIdx.x * 256 + threadIdx.x;   // row over NHW
    float l = 0.f, a = 0.f;
#pragma unroll
    for (int c = 0; c < QSPLIT; ++c) {
        l += ws[WS_PL + (size_t)c * NHW + i];
        a += ws[WS_PA + (size_t)c * NHW + i];
    }
    float att = a / l;
    out_att[i] = att;
    ws[WS_ATT + i] = att;
}

// ---------------------------------------------------------------------------
// Kernel 4: epilogue  out[n][c][p] = att[n][p]*gamma + x[n][c][p], float4.
// ---------------------------------------------------------------------------
__global__ __launch_bounds__(256) void epilogue_kernel(
    const float* __restrict__ x, const float* __restrict__ ws,
    const float* __restrict__ gamma, float* __restrict__ out)
{
    size_t i = (size_t)blockIdx.x * 256 + threadIdx.x;  // float4 index
    size_t e = i * 4;
    int n = (int)(e >> 18);          // / (CH*HWP)
    int p = (int)(e & (HWP - 1));
    float gm = gamma[0];
    float4 a4 = *(const float4*)(ws + WS_ATT + (size_t)n * HWP + p);
    float4 x4 = *(const float4*)(x + e);
    float4 o;
    o.x = fmaf(a4.x, gm, x4.x);
    o.y = fmaf(a4.y, gm, x4.y);
    o.z = fmaf(a4.z, gm, x4.z);
    o.w = fmaf(a4.w, gm, x4.w);
    *(float4*)(out + e) = o;
}

extern "C" void kernel_launch(void* const* d_in, const int* in_sizes, int n_in,
                              void* d_out, int out_size, void* d_ws, size_t ws_size,
                              hipStream_t stream) {
    const float* x     = (const float*)d_in[0];
    const float* Wf    = (const float*)d_in[1];
    const float* bf    = (const float*)d_in[2];
    const float* Wg    = (const float*)d_in[3];
    const float* bg    = (const float*)d_in[4];
    const float* Ws    = (const float*)d_in[5];
    const float* bs    = (const float*)d_in[6];
    const float* gamma = (const float*)d_in[7];
    float* out = (float*)d_out;
    float* ws  = (float*)d_ws;

    // d_out layout: att_map [NB*HWP] then output [NB*CH*HWP]
    proj_kernel<<<NB * (HWP / 256), 256, 0, stream>>>(x, Wf, bf, Wg, bg, Ws, bs, ws);
    attn_mfma_kernel<<<NB * 16 * QSPLIT, 256, 0, stream>>>(ws);
    merge_kernel<<<NHW / 256, 256, 0, stream>>>(ws, out);
    epilogue_kernel<<<(NB * CH * HWP / 4) / 256, 256, 0, stream>>>(
        x, ws, gamma, out + NHW);
}